// Round 7
// baseline (388.653 us; speedup 1.0000x reference)
//
#include <hip/hip_runtime.h>

// STS linear attention, fp32.  B=4, N=4096, H=8, D=64, M=64.
// phase1 : 1024 blocks, each a full 64x64 KV tile over 128 rows. LDS double-buffered
//          chunks of 32 rows (reg-staged, fmap(K) applied once at staging).
//          Partial tiles (16.8 MB) -> d_out; partial Ksum -> d_ws.
// phase1b: sum 32 partials per (b,h) -> KV [32][64][64] + Ksum [32][64] in d_ws.
// phase2 : out[n,m] = (sum_d f(Q)[n,d]*KV[m,d]) / (sum_d f(Q)[n,d]*Ksum[d] + eps).
//          Thread = 1 row x 16 m; full Q row staged in regs.

#define EPSC 1e-6f

constexpr int Bq = 4;
constexpr int Nq = 4096;
constexpr int Hq = 8;
constexpr int Dq = 64;
constexpr int Mq = 64;
constexpr int BH = Bq * Hq;          // 32
constexpr int RSTR = Hq * Dq;        // 512 floats between consecutive n (both K and V)
constexpr int TILESZ = Mq * Dq;      // 4096 floats per tile

__device__ __forceinline__ float fmap(float x) {
    return x > 0.0f ? x + 1.0f : __expf(x);   // elu(x)+1
}

// ---------------- Phase 1 ----------------
// grid = 1024 (= BH*32) blocks x 256 thr. Block: bh = blk>>5, rows (blk&31)*128..+128.
// Wave w owns m in [16w,16w+16); thread tile 4m x 4d (tm=lane>>4, td=lane&15).
constexpr int P1_CH = 32;            // rows per chunk
constexpr int P1_NCH = 4;            // chunks per block (128 rows)

__global__ __launch_bounds__(256)
void phase1_kv(const float* __restrict__ Kp, const float* __restrict__ Vp,
               float* __restrict__ partKV, float* __restrict__ partKS)
{
    __shared__ float kbuf[2][P1_CH][68];   // fmapped K, padded stride 68
    __shared__ float vbuf[2][P1_CH][68];

    const int blk = blockIdx.x;
    const int bh = blk >> 5, ck = blk & 31;
    const int b  = bh >> 3,  h  = bh & 7;
    const int tid = threadIdx.x;
    const int w = tid >> 6, lane = tid & 63;
    const int tm = lane >> 4;            // 0..3
    const int td = lane & 15;            // 0..15
    const int m0 = w * 16 + tm * 4;      // this thread's m base

    // staging: row sr = tid>>3 (0..31), cols sc=(tid&7)*4 and sc+32
    const int sr = tid >> 3, sc = (tid & 7) * 4;

    const float* Kbase = Kp + ((size_t)(b * Nq + ck * 128) * Hq + h) * Dq;
    const float* Vbase = Vp + ((size_t)(b * Nq + ck * 128) * Hq + h) * Mq;

    float4 ka, kb4, va, vb4;
    // prologue: stage chunk 0
    {
        const float* kr = Kbase + (size_t)sr * RSTR;
        const float* vr = Vbase + (size_t)sr * RSTR;
        ka  = *(const float4*)(kr + sc);
        kb4 = *(const float4*)(kr + sc + 32);
        va  = *(const float4*)(vr + sc);
        vb4 = *(const float4*)(vr + sc + 32);
        *(float4*)&kbuf[0][sr][sc]      = make_float4(fmap(ka.x),  fmap(ka.y),  fmap(ka.z),  fmap(ka.w));
        *(float4*)&kbuf[0][sr][sc + 32] = make_float4(fmap(kb4.x), fmap(kb4.y), fmap(kb4.z), fmap(kb4.w));
        *(float4*)&vbuf[0][sr][sc]      = va;
        *(float4*)&vbuf[0][sr][sc + 32] = vb4;
    }
    __syncthreads();

    float acc[4][4];                     // [mi][di]
    #pragma unroll
    for (int i = 0; i < 4; ++i)
        #pragma unroll
        for (int j = 0; j < 4; ++j) acc[i][j] = 0.0f;
    float ks0 = 0.f, ks1 = 0.f, ks2 = 0.f, ks3 = 0.f;

    for (int c = 0; c < P1_NCH; ++c) {
        const int cur = c & 1, nxt = cur ^ 1;
        if (c + 1 < P1_NCH) {            // issue next chunk's loads EARLY (hide under compute)
            const float* kr = Kbase + (size_t)((c + 1) * P1_CH + sr) * RSTR;
            const float* vr = Vbase + (size_t)((c + 1) * P1_CH + sr) * RSTR;
            ka  = *(const float4*)(kr + sc);
            kb4 = *(const float4*)(kr + sc + 32);
            va  = *(const float4*)(vr + sc);
            vb4 = *(const float4*)(vr + sc + 32);
        }
        #pragma unroll
        for (int r = 0; r < P1_CH; ++r) {
            const float4 kq = *(const float4*)&kbuf[cur][r][td * 4];
            const float4 vq = *(const float4*)&vbuf[cur][r][m0];
            acc[0][0] = fmaf(vq.x, kq.x, acc[0][0]);
            acc[0][1] = fmaf(vq.x, kq.y, acc[0][1]);
            acc[0][2] = fmaf(vq.x, kq.z, acc[0][2]);
            acc[0][3] = fmaf(vq.x, kq.w, acc[0][3]);
            acc[1][0] = fmaf(vq.y, kq.x, acc[1][0]);
            acc[1][1] = fmaf(vq.y, kq.y, acc[1][1]);
            acc[1][2] = fmaf(vq.y, kq.z, acc[1][2]);
            acc[1][3] = fmaf(vq.y, kq.w, acc[1][3]);
            acc[2][0] = fmaf(vq.z, kq.x, acc[2][0]);
            acc[2][1] = fmaf(vq.z, kq.y, acc[2][1]);
            acc[2][2] = fmaf(vq.z, kq.z, acc[2][2]);
            acc[2][3] = fmaf(vq.z, kq.w, acc[2][3]);
            acc[3][0] = fmaf(vq.w, kq.x, acc[3][0]);
            acc[3][1] = fmaf(vq.w, kq.y, acc[3][1]);
            acc[3][2] = fmaf(vq.w, kq.z, acc[3][2]);
            acc[3][3] = fmaf(vq.w, kq.w, acc[3][3]);
            if (w == 0) { ks0 += kq.x; ks1 += kq.y; ks2 += kq.z; ks3 += kq.w; }
        }
        if (c + 1 < P1_NCH) {
            // waitcnt lands here (first use of staged regs)
            *(float4*)&kbuf[nxt][sr][sc]      = make_float4(fmap(ka.x),  fmap(ka.y),  fmap(ka.z),  fmap(ka.w));
            *(float4*)&kbuf[nxt][sr][sc + 32] = make_float4(fmap(kb4.x), fmap(kb4.y), fmap(kb4.z), fmap(kb4.w));
            *(float4*)&vbuf[nxt][sr][sc]      = va;
            *(float4*)&vbuf[nxt][sr][sc + 32] = vb4;
            __syncthreads();             // buf[nxt] staged; all waves past reads of it
        }
    }

    float* dst = partKV + (size_t)blk * TILESZ;
    #pragma unroll
    for (int mi = 0; mi < 4; ++mi)
        *(float4*)&dst[(m0 + mi) * Dq + td * 4] =
            make_float4(acc[mi][0], acc[mi][1], acc[mi][2], acc[mi][3]);
    if (w == 0 && tm == 0)
        *(float4*)&partKS[(size_t)blk * Dq + td * 4] = make_float4(ks0, ks1, ks2, ks3);
}

// ---------------- Phase 1b: sum 32 partials per bh ----------------
// grid = 512 blocks x 256 thr. Block = (bh, sixteenth). Thread = one float.
__global__ __launch_bounds__(256)
void phase1b_reduce(const float* __restrict__ partKV, const float* __restrict__ partKS,
                    float* __restrict__ KV, float* __restrict__ KS)
{
    const int bh = blockIdx.x >> 4, six = blockIdx.x & 15;
    const int t  = threadIdx.x;
    const int off = six * 256 + t;
    const float* src = partKV + (size_t)(bh * 32) * TILESZ + off;

    float a = 0.0f;
    #pragma unroll
    for (int p = 0; p < 32; ++p)
        a += src[(size_t)p * TILESZ];
    KV[(size_t)bh * TILESZ + off] = a;

    if (six == 0 && t < Dq) {
        const float* ksp = partKS + (size_t)(bh * 32) * Dq + t;
        float s = 0.0f;
        #pragma unroll
        for (int p = 0; p < 32; ++p)
            s += ksp[(size_t)p * Dq];
        KS[bh * Dq + t] = s;
    }
}

// ---------------- Phase 2 ----------------
// grid = 2048 blocks x 256 thr. Block: bh = blk>>6, rows (blk&63)*64..+64.
// Thread = 1 row (rt = tid>>2) x 16 contiguous m (mg = tid&3, m = mg*16+mi).
__global__ __launch_bounds__(256)
void phase2_out(const float* __restrict__ Qp, const float* __restrict__ KV,
                const float* __restrict__ KS, float* __restrict__ Out)
{
    const int blk = blockIdx.x;
    const int bh = blk >> 6, ck = blk & 63;
    const int b  = bh >> 3,  h  = bh & 7;
    const int rt = threadIdx.x >> 2, mg = threadIdx.x & 3;
    const int row = ck * 64 + rt;

    const float* Qb = Qp + ((size_t)(b * Nq + row) * Hq + h) * Dq;
    float4 qf[16];
    #pragma unroll
    for (int j = 0; j < 16; ++j) qf[j] = *(const float4*)(Qb + j * 4);
    #pragma unroll
    for (int j = 0; j < 16; ++j) {
        qf[j].x = fmap(qf[j].x); qf[j].y = fmap(qf[j].y);
        qf[j].z = fmap(qf[j].z); qf[j].w = fmap(qf[j].w);
    }

    const float* KVb = KV + (size_t)bh * TILESZ + (mg * 16) * Dq;
    const float* KSb = KS + bh * Dq;

    float acc[16];
    #pragma unroll
    for (int i = 0; i < 16; ++i) acc[i] = 0.0f;
    float z0 = 0.f, z1 = 0.f, z2 = 0.f, z3 = 0.f;

    #pragma unroll
    for (int j = 0; j < 16; ++j) {       // d4-step
        const float4 q   = qf[j];
        const float4 ks4 = *(const float4*)(KSb + j * 4);
        z0 = fmaf(q.x, ks4.x, z0);
        z1 = fmaf(q.y, ks4.y, z1);
        z2 = fmaf(q.z, ks4.z, z2);
        z3 = fmaf(q.w, ks4.w, z3);
        #pragma unroll
        for (int mi = 0; mi < 16; ++mi) {
            const float4 kv4 = *(const float4*)(KVb + mi * Dq + j * 4);
            acc[mi] = fmaf(q.x, kv4.x, acc[mi]);
            acc[mi] = fmaf(q.y, kv4.y, acc[mi]);
            acc[mi] = fmaf(q.z, kv4.z, acc[mi]);
            acc[mi] = fmaf(q.w, kv4.w, acc[mi]);
        }
    }

    const float z = 1.0f / (z0 + z1 + z2 + z3 + EPSC);
    float* Ob = Out + ((size_t)(b * Nq + row) * Hq + h) * Mq + mg * 16;
    #pragma unroll
    for (int jj = 0; jj < 4; ++jj)
        *(float4*)(Ob + jj * 4) = make_float4(acc[jj*4+0] * z, acc[jj*4+1] * z,
                                              acc[jj*4+2] * z, acc[jj*4+3] * z);
}

extern "C" void kernel_launch(void* const* d_in, const int* in_sizes, int n_in,
                              void* d_out, int out_size, void* d_ws, size_t ws_size,
                              hipStream_t stream)
{
    (void)in_sizes; (void)n_in; (void)out_size; (void)ws_size;
    const float* Q = (const float*)d_in[0];
    const float* K = (const float*)d_in[1];
    const float* V = (const float*)d_in[2];
    float* out = (float*)d_out;

    // d_out doubles as scratch for 1024 partial KV tiles (16.8 MB <= 33.5 MB);
    // phase2 overwrites it with the final result.
    float* partKV = out;                                   // [1024][4096]
    float* wsKV   = (float*)d_ws;                          // [32][4096]  = 512 KB
    float* wsKS   = wsKV + (size_t)BH * TILESZ;            // [32][64]    = 8 KB
    float* partKS = wsKS + (size_t)BH * Dq;                // [1024][64]  = 256 KB

    phase1_kv<<<BH * 32, 256, 0, stream>>>(K, V, partKV, partKS);
    phase1b_reduce<<<BH * 16, 256, 0, stream>>>(partKV, partKS, wsKV, wsKS);
    phase2_out<<<BH * 64, 256, 0, stream>>>(Q, wsKV, wsKS, out);
}

// Round 8
// 200.565 us; speedup vs baseline: 1.9378x; 1.9378x over previous
//
#include <hip/hip_runtime.h>

// STS linear attention, fp32.  B=4, N=4096, H=8, D=64, M=64.
// phase1 : 1024 blocks, each a full 64x64 KV tile over 128 rows. LDS double-buffered
//          chunks of 32 rows (reg-staged, fmap(K) applied once at staging).
// phase1b: sum 32 partials per (b,h) -> KV [32][64][64] + Ksum [32][64] in d_ws.
// phase2 : KV tile in LDS (XOR-swizzled, conflict-free). Thread = 4 rows x 8 m.
//          Q streamed from global with one-step-ahead prefetch.

#define EPSC 1e-6f

constexpr int Bq = 4;
constexpr int Nq = 4096;
constexpr int Hq = 8;
constexpr int Dq = 64;
constexpr int Mq = 64;
constexpr int BH = Bq * Hq;          // 32
constexpr int RSTR = Hq * Dq;        // 512 floats between consecutive n (both K and V)
constexpr int TILESZ = Mq * Dq;      // 4096 floats per tile

__device__ __forceinline__ float fmap(float x) {
    return x > 0.0f ? x + 1.0f : __expf(x);   // elu(x)+1
}

// ---------------- Phase 1 (unchanged from R4) ----------------
constexpr int P1_CH = 32;            // rows per chunk
constexpr int P1_NCH = 4;            // chunks per block (128 rows)

__global__ __launch_bounds__(256)
void phase1_kv(const float* __restrict__ Kp, const float* __restrict__ Vp,
               float* __restrict__ partKV, float* __restrict__ partKS)
{
    __shared__ float kbuf[2][P1_CH][68];   // fmapped K, padded stride 68
    __shared__ float vbuf[2][P1_CH][68];

    const int blk = blockIdx.x;
    const int bh = blk >> 5, ck = blk & 31;
    const int b  = bh >> 3,  h  = bh & 7;
    const int tid = threadIdx.x;
    const int w = tid >> 6, lane = tid & 63;
    const int tm = lane >> 4;            // 0..3
    const int td = lane & 15;            // 0..15
    const int m0 = w * 16 + tm * 4;      // this thread's m base

    const int sr = tid >> 3, sc = (tid & 7) * 4;

    const float* Kbase = Kp + ((size_t)(b * Nq + ck * 128) * Hq + h) * Dq;
    const float* Vbase = Vp + ((size_t)(b * Nq + ck * 128) * Hq + h) * Mq;

    float4 ka, kb4, va, vb4;
    {
        const float* kr = Kbase + (size_t)sr * RSTR;
        const float* vr = Vbase + (size_t)sr * RSTR;
        ka  = *(const float4*)(kr + sc);
        kb4 = *(const float4*)(kr + sc + 32);
        va  = *(const float4*)(vr + sc);
        vb4 = *(const float4*)(vr + sc + 32);
        *(float4*)&kbuf[0][sr][sc]      = make_float4(fmap(ka.x),  fmap(ka.y),  fmap(ka.z),  fmap(ka.w));
        *(float4*)&kbuf[0][sr][sc + 32] = make_float4(fmap(kb4.x), fmap(kb4.y), fmap(kb4.z), fmap(kb4.w));
        *(float4*)&vbuf[0][sr][sc]      = va;
        *(float4*)&vbuf[0][sr][sc + 32] = vb4;
    }
    __syncthreads();

    float acc[4][4];
    #pragma unroll
    for (int i = 0; i < 4; ++i)
        #pragma unroll
        for (int j = 0; j < 4; ++j) acc[i][j] = 0.0f;
    float ks0 = 0.f, ks1 = 0.f, ks2 = 0.f, ks3 = 0.f;

    for (int c = 0; c < P1_NCH; ++c) {
        const int cur = c & 1, nxt = cur ^ 1;
        if (c + 1 < P1_NCH) {
            const float* kr = Kbase + (size_t)((c + 1) * P1_CH + sr) * RSTR;
            const float* vr = Vbase + (size_t)((c + 1) * P1_CH + sr) * RSTR;
            ka  = *(const float4*)(kr + sc);
            kb4 = *(const float4*)(kr + sc + 32);
            va  = *(const float4*)(vr + sc);
            vb4 = *(const float4*)(vr + sc + 32);
        }
        #pragma unroll
        for (int r = 0; r < P1_CH; ++r) {
            const float4 kq = *(const float4*)&kbuf[cur][r][td * 4];
            const float4 vq = *(const float4*)&vbuf[cur][r][m0];
            acc[0][0] = fmaf(vq.x, kq.x, acc[0][0]);
            acc[0][1] = fmaf(vq.x, kq.y, acc[0][1]);
            acc[0][2] = fmaf(vq.x, kq.z, acc[0][2]);
            acc[0][3] = fmaf(vq.x, kq.w, acc[0][3]);
            acc[1][0] = fmaf(vq.y, kq.x, acc[1][0]);
            acc[1][1] = fmaf(vq.y, kq.y, acc[1][1]);
            acc[1][2] = fmaf(vq.y, kq.z, acc[1][2]);
            acc[1][3] = fmaf(vq.y, kq.w, acc[1][3]);
            acc[2][0] = fmaf(vq.z, kq.x, acc[2][0]);
            acc[2][1] = fmaf(vq.z, kq.y, acc[2][1]);
            acc[2][2] = fmaf(vq.z, kq.z, acc[2][2]);
            acc[2][3] = fmaf(vq.z, kq.w, acc[2][3]);
            acc[3][0] = fmaf(vq.w, kq.x, acc[3][0]);
            acc[3][1] = fmaf(vq.w, kq.y, acc[3][1]);
            acc[3][2] = fmaf(vq.w, kq.z, acc[3][2]);
            acc[3][3] = fmaf(vq.w, kq.w, acc[3][3]);
            if (w == 0) { ks0 += kq.x; ks1 += kq.y; ks2 += kq.z; ks3 += kq.w; }
        }
        if (c + 1 < P1_NCH) {
            *(float4*)&kbuf[nxt][sr][sc]      = make_float4(fmap(ka.x),  fmap(ka.y),  fmap(ka.z),  fmap(ka.w));
            *(float4*)&kbuf[nxt][sr][sc + 32] = make_float4(fmap(kb4.x), fmap(kb4.y), fmap(kb4.z), fmap(kb4.w));
            *(float4*)&vbuf[nxt][sr][sc]      = va;
            *(float4*)&vbuf[nxt][sr][sc + 32] = vb4;
            __syncthreads();
        }
    }

    float* dst = partKV + (size_t)blk * TILESZ;
    #pragma unroll
    for (int mi = 0; mi < 4; ++mi)
        *(float4*)&dst[(m0 + mi) * Dq + td * 4] =
            make_float4(acc[mi][0], acc[mi][1], acc[mi][2], acc[mi][3]);
    if (w == 0 && tm == 0)
        *(float4*)&partKS[(size_t)blk * Dq + td * 4] = make_float4(ks0, ks1, ks2, ks3);
}

// ---------------- Phase 1b (unchanged from R4) ----------------
__global__ __launch_bounds__(256)
void phase1b_reduce(const float* __restrict__ partKV, const float* __restrict__ partKS,
                    float* __restrict__ KV, float* __restrict__ KS)
{
    const int bh = blockIdx.x >> 4, six = blockIdx.x & 15;
    const int t  = threadIdx.x;
    const int off = six * 256 + t;
    const float* src = partKV + (size_t)(bh * 32) * TILESZ + off;

    float a = 0.0f;
    #pragma unroll
    for (int p = 0; p < 32; ++p)
        a += src[(size_t)p * TILESZ];
    KV[(size_t)bh * TILESZ + off] = a;

    if (six == 0 && t < Dq) {
        const float* ksp = partKS + (size_t)(bh * 32) * Dq + t;
        float s = 0.0f;
        #pragma unroll
        for (int p = 0; p < 32; ++p)
            s += ksp[(size_t)p * Dq];
        KS[bh * Dq + t] = s;
    }
}

// ---------------- Phase 2 (new: LDS KV, swizzled, 4 rows x 8 m) ----------------
// grid = 1024 blocks x 256 thr. Block: bh = blk>>5, rows (blk&31)*128..+128.
// Thread: mg = tid&7 -> m in [8mg, 8mg+8); rt = tid>>3 -> rows rt*4..+4.
// LDS: sKV element (m, float4-col j) stored at column (j ^ (m>>3)) -> the 8
// mg-lanes of a wave read 8 distinct bank-quads per instruction (conflict-free).
__global__ __launch_bounds__(256)
void phase2_out(const float* __restrict__ Qp, const float* __restrict__ KV,
                const float* __restrict__ KS, float* __restrict__ Out)
{
    __shared__ float sKV[Mq * Dq];   // 16 KB, swizzled
    __shared__ float sKS[Dq];

    const int blk = blockIdx.x;
    const int bh = blk >> 5, ck = blk & 31;
    const int b  = bh >> 3,  h  = bh & 7;
    const int tid = threadIdx.x;

    // stage KV (swizzled) + KS
    {
        const float4* kvsrc = (const float4*)(KV + (size_t)bh * TILESZ);
        #pragma unroll
        for (int it = 0; it < 4; ++it) {
            const int flat = tid + it * 256;       // float4 index 0..1023
            const int m = flat >> 4, j = flat & 15;
            const float4 v = kvsrc[flat];
            *(float4*)&sKV[m * Dq + ((j ^ (m >> 3)) << 2)] = v;
        }
        if (tid < 16)
            ((float4*)sKS)[tid] = ((const float4*)(KS + bh * Dq))[tid];
    }
    __syncthreads();

    const int mg = tid & 7;              // m block: m = mg*8 + mi
    const int rt = tid >> 3;             // 0..31
    const int row0 = ck * 128 + rt * 4;
    const float* Qb = Qp + ((size_t)(b * Nq + row0) * Hq + h) * Dq;

    float acc[4][8];
    float zac[4] = {0.f, 0.f, 0.f, 0.f};
    #pragma unroll
    for (int i = 0; i < 4; ++i)
        #pragma unroll
        for (int j = 0; j < 8; ++j) acc[i][j] = 0.0f;

    float4 qa[4], qb[4];                 // software-pipelined Q (static indexing via full unroll)
    #pragma unroll
    for (int i = 0; i < 4; ++i) qa[i] = *(const float4*)(Qb + (size_t)i * RSTR);

    #pragma unroll
    for (int j = 0; j < 16; ++j) {       // d4-step; j is compile-time constant
        float4* qc = (j & 1) ? qb : qa;  // folds statically under full unroll
        float4* qn = (j & 1) ? qa : qb;
        if (j < 15) {
            #pragma unroll
            for (int i = 0; i < 4; ++i)
                qn[i] = *(const float4*)(Qb + (size_t)i * RSTR + (j + 1) * 4);
        }
        const float4 ks4 = *(const float4*)&sKS[j * 4];
        float4 kv[8];
        const int col = ((j ^ mg) << 2);
        #pragma unroll
        for (int mi = 0; mi < 8; ++mi)
            kv[mi] = *(const float4*)&sKV[(mg * 8 + mi) * Dq + col];
        #pragma unroll
        for (int i = 0; i < 4; ++i) {
            const float q0 = fmap(qc[i].x), q1 = fmap(qc[i].y);
            const float q2 = fmap(qc[i].z), q3 = fmap(qc[i].w);
            zac[i] = fmaf(q0, ks4.x, zac[i]);
            zac[i] = fmaf(q1, ks4.y, zac[i]);
            zac[i] = fmaf(q2, ks4.z, zac[i]);
            zac[i] = fmaf(q3, ks4.w, zac[i]);
            #pragma unroll
            for (int mi = 0; mi < 8; ++mi) {
                acc[i][mi] = fmaf(q0, kv[mi].x, acc[i][mi]);
                acc[i][mi] = fmaf(q1, kv[mi].y, acc[i][mi]);
                acc[i][mi] = fmaf(q2, kv[mi].z, acc[i][mi]);
                acc[i][mi] = fmaf(q3, kv[mi].w, acc[i][mi]);
            }
        }
    }

    float* Ob = Out + ((size_t)(b * Nq + row0) * Hq + h) * Mq + mg * 8;
    #pragma unroll
    for (int i = 0; i < 4; ++i) {
        const float z = 1.0f / (zac[i] + EPSC);
        *(float4*)(Ob + (size_t)i * RSTR)     = make_float4(acc[i][0] * z, acc[i][1] * z,
                                                            acc[i][2] * z, acc[i][3] * z);
        *(float4*)(Ob + (size_t)i * RSTR + 4) = make_float4(acc[i][4] * z, acc[i][5] * z,
                                                            acc[i][6] * z, acc[i][7] * z);
    }
}

extern "C" void kernel_launch(void* const* d_in, const int* in_sizes, int n_in,
                              void* d_out, int out_size, void* d_ws, size_t ws_size,
                              hipStream_t stream)
{
    (void)in_sizes; (void)n_in; (void)out_size; (void)ws_size;
    const float* Q = (const float*)d_in[0];
    const float* K = (const float*)d_in[1];
    const float* V = (const float*)d_in[2];
    float* out = (float*)d_out;

    // d_out doubles as scratch for 1024 partial KV tiles (16.8 MB <= 33.5 MB);
    // phase2 overwrites it with the final result.
    float* partKV = out;                                   // [1024][4096]
    float* wsKV   = (float*)d_ws;                          // [32][4096]  = 512 KB
    float* wsKS   = wsKV + (size_t)BH * TILESZ;            // [32][64]    = 8 KB
    float* partKS = wsKS + (size_t)BH * Dq;                // [1024][64]  = 256 KB

    phase1_kv<<<BH * 32, 256, 0, stream>>>(K, V, partKV, partKS);
    phase1b_reduce<<<BH * 16, 256, 0, stream>>>(partKV, partKS, wsKV, wsKS);
    phase2_out<<<BH * 32, 256, 0, stream>>>(Q, wsKV, wsKS, out);
}